// Round 5
// baseline (2203.559 us; speedup 1.0000x reference)
//
#include <hip/hip_runtime.h>
#include <stdint.h>

// TernaryMLP: relu-chain of h @ (gamma*T).T + b, T ternary (exact in bf16).
// gamma via deterministic fp64 2-stage reduction; bf16 MFMA GEMMs.
// Layers 1-3: 256^2-tile GEMM, 16x16x32 MFMA, 4-phase/K-tile schedule where
//   each phase's ds_reads feed the NEXT phase's MFMA (read-ahead by one phase,
//   R2 register footprint: 16 fragment regs). T1+T2+T4+T5.
// Layer 4 (N=1024): 128^2 2-phase GEMM with XOR swizzle.

#define EPSQ 1e-5f

typedef __attribute__((ext_vector_type(8))) short bf16x8;   // 8 bf16 = 4 VGPR
typedef __attribute__((ext_vector_type(4))) float f32x4;    // MFMA accum

__device__ __forceinline__ uint16_t f2bf(float f) {
    uint32_t u = __float_as_uint(f);
    return (uint16_t)((u + 0x7FFFu + ((u >> 16) & 1u)) >> 16);
}

__device__ __forceinline__ void load_lds16(const uint16_t* g, char* l) {
    __builtin_amdgcn_global_load_lds((const __attribute__((address_space(1))) void*)g,
                                     (__attribute__((address_space(3))) void*)l,
                                     16, 0, 0);
}

// ---------------- gamma = mean(|W|), deterministic fp64 2-stage ----------------
__global__ void absmean_stage1(const float* __restrict__ w, long long n,
                               double* __restrict__ partial) {
    double acc = 0.0;
    const long long tid = (long long)blockIdx.x * blockDim.x + threadIdx.x;
    const long long stride = (long long)gridDim.x * blockDim.x;
    const float4* w4 = (const float4*)w;
    const long long n4 = n >> 2;
    for (long long i = tid; i < n4; i += stride) {
        float4 v = w4[i];
        acc += (double)fabsf(v.x) + (double)fabsf(v.y) +
               (double)fabsf(v.z) + (double)fabsf(v.w);
    }
    __shared__ double sm[256];
    sm[threadIdx.x] = acc;
    __syncthreads();
    for (int s = 128; s > 0; s >>= 1) {
        if ((int)threadIdx.x < s) sm[threadIdx.x] += sm[threadIdx.x + s];
        __syncthreads();
    }
    if (threadIdx.x == 0) partial[blockIdx.x] = sm[0];
}

__global__ void absmean_stage2(const double* __restrict__ partial,
                               float* __restrict__ gammas) {
    const int m = blockIdx.x;
    __shared__ double sm[256];
    double acc = partial[m * 512 + threadIdx.x] + partial[m * 512 + 256 + threadIdx.x];
    sm[threadIdx.x] = acc;
    __syncthreads();
    for (int s = 128; s > 0; s >>= 1) {
        if ((int)threadIdx.x < s) sm[threadIdx.x] += sm[threadIdx.x + s];
        __syncthreads();
    }
    if (threadIdx.x == 0) {
        const double n = (m == 3) ? 1000.0 * 4096.0 : 4096.0 * 4096.0;
        gammas[m] = (float)(sm[0] / n);
    }
}

// ---------------- quantize W -> ternary bf16 (+ zero padding rows) ----------------
__global__ void quantize_w(const float* __restrict__ w, uint16_t* __restrict__ q,
                           long long n_valid, long long n_total,
                           const float* __restrict__ gammas, int gi) {
    const float d = gammas[gi] + EPSQ;
    const long long stride = (long long)gridDim.x * blockDim.x * 4;
    for (long long i = ((long long)blockIdx.x * blockDim.x + threadIdx.x) * 4;
         i < n_total; i += stride) {
        float4 v = make_float4(0.f, 0.f, 0.f, 0.f);
        if (i < n_valid) v = *(const float4*)(w + i);
        ushort4 o;
        o.x = f2bf(fminf(1.f, fmaxf(-1.f, rintf(v.x / d))));
        o.y = f2bf(fminf(1.f, fmaxf(-1.f, rintf(v.y / d))));
        o.z = f2bf(fminf(1.f, fmaxf(-1.f, rintf(v.z / d))));
        o.w = f2bf(fminf(1.f, fmaxf(-1.f, rintf(v.w / d))));
        *(ushort4*)(q + i) = o;
    }
}

// ---------------- x (fp32) -> bf16 ----------------
__global__ void cvt_bf16(const float* __restrict__ x, uint16_t* __restrict__ y,
                         long long n) {
    const long long stride = (long long)gridDim.x * blockDim.x * 4;
    for (long long i = ((long long)blockIdx.x * blockDim.x + threadIdx.x) * 4;
         i < n; i += stride) {
        float4 v = *(const float4*)(x + i);
        ushort4 o;
        o.x = f2bf(v.x); o.y = f2bf(v.y); o.z = f2bf(v.z); o.w = f2bf(v.w);
        *(ushort4*)(y + i) = o;
    }
}

// ================= 256x256-tile pipelined GEMM (layers 1-3) =================
// C[m][n] = epi(gamma * sum_k A[m][k]*Bt[n][k] + bias[n])
// 512 thr = 8 waves (2M x 4N), per-wave 128x64 via 8x4 frags of 16x16.
// LDS 128KB: buf[2] x {A0,A1,B0,B1} of 128x64 bf16 (16KB each).
// Swizzle: LDS[r][cb] holds global[r][cb ^ ((r&7)<<4)].
// Phases (per K-tile): p0=m0-3*kk0, p1=m4-7*kk0, p2=m0-3*kk1, p3=m4-7*kk1.
// Each phase issues reads for the NEXT phase; MFMA uses prev-phase regs.
// Stages: p0->A1(t+1), p1->B0(t+2), p2->B1(t+2), p3->A0(t+2).
// Publish: lgkmcnt(0)+vmcnt(4)+barrier at p2-end (tail vmcnt(0)).
template<bool RELU, bool BF16OUT>
__global__ __launch_bounds__(512, 2) void gemm256(
    const uint16_t* __restrict__ A, const uint16_t* __restrict__ Bt,
    const float* __restrict__ bias, const float* __restrict__ gammas, int gi,
    void* __restrict__ Cp, int K, int Nstore, int Nvalid, int gridN)
{
    __shared__ char lds[131072];

    const int tid  = threadIdx.x;
    const int lane = tid & 63;
    const int wid  = tid >> 6;
    const int wr   = wid >> 2;     // 0..1
    const int wc   = wid & 3;      // 0..3

    // T1: bijective XCD swizzle (nwg % 8 == 0)
    const int nwg = gridDim.x;
    const int logical = ((int)blockIdx.x & 7) * (nwg >> 3) + ((int)blockIdx.x >> 3);
    const long long tileM = (long long)(logical / gridN) * 256;
    const long long tileN = (long long)(logical % gridN) * 256;

    // ---- staging (inverse-swizzled global source, linear LDS dest) ----
    const int srow = tid >> 3;
    const int scol = (((tid & 7) ^ ((tid >> 3) & 7)) << 3);
    const uint16_t* As = A  + (tileM + srow) * (long long)K + scol;
    const uint16_t* Bs = Bt + (tileN + srow) * (long long)K + scol;

    auto stageA = [&](int par, int h, int k0) {
        char* dst = lds + par * 65536 + h * 16384 + wid * 1024;
        const uint16_t* s = As + (long long)(h * 128) * K + k0;
        load_lds16(s, dst);
        load_lds16(s + (long long)64 * K, dst + 8192);
    };
    auto stageB = [&](int par, int h, int k0) {
        char* dst = lds + par * 65536 + 32768 + h * 16384 + wid * 1024;
        const uint16_t* s = Bs + (long long)(h * 128) * K + k0;
        load_lds16(s, dst);
        load_lds16(s + (long long)64 * K, dst + 8192);
    };

    // ---- fragment read addressing (16x16x32; row = lane&15, kq = lane>>4) ----
    const int lr  = lane & 15;
    const int cb0 = (lane >> 4) << 4;          // 0,16,32,48
    const int swz = (lane & 7) << 4;           // row&7 == lane&7
    const int Aoff = wr * 16384 + lr * 128;
    const int Boff = 32768 + (wc >> 1) * 16384 + ((wc & 1) * 64 + lr) * 128;

    auto rdA = [&](int par, int m, int kk) -> bf16x8 {
        return *(const bf16x8*)(lds + par * 65536 + Aoff + m * 2048 +
                                ((kk * 64 + cb0) ^ swz));
    };
    auto rdB = [&](int par, int n, int kk) -> bf16x8 {
        return *(const bf16x8*)(lds + par * 65536 + Boff + n * 2048 +
                                ((kk * 64 + cb0) ^ swz));
    };

    auto MF = [](bf16x8 a, bf16x8 b, f32x4 c) -> f32x4 {
        return __builtin_amdgcn_mfma_f32_16x16x32_bf16(a, b, c, 0, 0, 0);
    };

    f32x4 acc[8][4];
#pragma unroll
    for (int m = 0; m < 8; ++m)
#pragma unroll
        for (int n = 0; n < 4; ++n)
            acc[m][n] = (f32x4){0.f, 0.f, 0.f, 0.f};

    bf16x8 a0[4], a1[4], bc[4], bn[4];   // 16 frags = 64 regs (same as R2)

    const int NT = K >> 6;

    // ---- prologue: stage t0 {A0,A1,B0,B1} + t1 {B0,B1,A0}; preload p0 regs ----
    stageA(0, 0, 0); stageA(0, 1, 0);
    stageB(0, 0, 0); stageB(0, 1, 0);
    stageB(1, 0, 64); stageB(1, 1, 64);
    stageA(1, 0, 64);
    asm volatile("s_waitcnt vmcnt(6)" ::: "memory");   // t0 fully staged
    __builtin_amdgcn_s_barrier();
    __builtin_amdgcn_sched_barrier(0);
#pragma unroll
    for (int m = 0; m < 4; ++m) a0[m] = rdA(0, m, 0);
#pragma unroll
    for (int n = 0; n < 4; ++n) bc[n] = rdB(0, n, 0);

    auto dotile = [&](int t, int par) {
        const int np = par ^ 1;

        // ==== p0: MFMA m0-3 x kk0 (a0,bc); read a1<-A[m4-7,kk0], bn<-B[kk1];
        //          stage A1(t+1)
#pragma unroll
        for (int m = 0; m < 4; ++m) a1[m] = rdA(par, 4 + m, 0);
#pragma unroll
        for (int n = 0; n < 4; ++n) bn[n] = rdB(par, n, 1);
        if (t + 1 < NT) stageA(np, 1, (t + 1) * 64);
        __builtin_amdgcn_sched_barrier(0);
        __builtin_amdgcn_s_setprio(1);
#pragma unroll
        for (int m = 0; m < 4; ++m)
#pragma unroll
            for (int n = 0; n < 4; ++n)
                acc[m][n] = MF(a0[m], bc[n], acc[m][n]);
        __builtin_amdgcn_s_setprio(0);
        asm volatile("s_waitcnt lgkmcnt(0)" ::: "memory");
        __builtin_amdgcn_sched_barrier(0);
        __builtin_amdgcn_s_barrier();

        // ==== p1: MFMA m4-7 x kk0 (a1,bc); read a0<-A[m0-3,kk1]; stage B0(t+2)
#pragma unroll
        for (int m = 0; m < 4; ++m) a0[m] = rdA(par, m, 1);
        if (t + 2 < NT) stageB(par, 0, (t + 2) * 64);
        __builtin_amdgcn_sched_barrier(0);
        __builtin_amdgcn_s_setprio(1);
#pragma unroll
        for (int m = 0; m < 4; ++m)
#pragma unroll
            for (int n = 0; n < 4; ++n)
                acc[4 + m][n] = MF(a1[m], bc[n], acc[4 + m][n]);
        __builtin_amdgcn_s_setprio(0);
        asm volatile("s_waitcnt lgkmcnt(0)" ::: "memory");
        __builtin_amdgcn_sched_barrier(0);
        __builtin_amdgcn_s_barrier();

        // ==== p2: MFMA m0-3 x kk1 (a0,bn); read a1<-A[m4-7,kk1]; stage B1(t+2)
        //          publish t+1 buffer: lgkm + counted vmcnt + barrier
#pragma unroll
        for (int m = 0; m < 4; ++m) a1[m] = rdA(par, 4 + m, 1);
        if (t + 2 < NT) stageB(par, 1, (t + 2) * 64);
        __builtin_amdgcn_sched_barrier(0);
        __builtin_amdgcn_s_setprio(1);
#pragma unroll
        for (int m = 0; m < 4; ++m)
#pragma unroll
            for (int n = 0; n < 4; ++n)
                acc[m][n] = MF(a0[m], bn[n], acc[m][n]);
        __builtin_amdgcn_s_setprio(0);
        asm volatile("s_waitcnt lgkmcnt(0)" ::: "memory");
        if (t + 2 < NT)
            asm volatile("s_waitcnt vmcnt(4)" ::: "memory");
        else if (t + 1 < NT)
            asm volatile("s_waitcnt vmcnt(0)" ::: "memory");
        __builtin_amdgcn_sched_barrier(0);
        __builtin_amdgcn_s_barrier();

        // ==== p3: MFMA m4-7 x kk1 (a1,bn); read next-tile a0<-A'[m0-3,kk0],
        //          bc<-B'[kk0] from buf np; stage A0(t+2)
        if (t + 1 < NT) {
#pragma unroll
            for (int m = 0; m < 4; ++m) a0[m] = rdA(np, m, 0);
#pragma unroll
            for (int n = 0; n < 4; ++n) bc[n] = rdB(np, n, 0);
        }
        if (t + 2 < NT) stageA(par, 0, (t + 2) * 64);
        __builtin_amdgcn_sched_barrier(0);
        __builtin_amdgcn_s_setprio(1);
#pragma unroll
        for (int m = 0; m < 4; ++m)
#pragma unroll
            for (int n = 0; n < 4; ++n)
                acc[4 + m][n] = MF(a1[m], bn[n], acc[4 + m][n]);
        __builtin_amdgcn_s_setprio(0);
        asm volatile("s_waitcnt lgkmcnt(0)" ::: "memory");
        __builtin_amdgcn_sched_barrier(0);
        __builtin_amdgcn_s_barrier();
    };

    for (int t = 0; t < NT; t += 2) {
        dotile(t, 0);
        dotile(t + 1, 1);
    }

    // ---- epilogue: C/D 16x16: col=lane&15, row=(lane>>4)*4+j ----
    const float g = gammas[gi];
    const int cr = (lane >> 4) << 2;
    const int cc = lane & 15;
#pragma unroll
    for (int m = 0; m < 8; ++m) {
        const long long row = tileM + wr * 128 + m * 16 + cr;
#pragma unroll
        for (int n = 0; n < 4; ++n) {
            const int col = (int)tileN + wc * 64 + n * 16 + cc;
            if (col < Nvalid) {
                const float bb = bias[col];
#pragma unroll
                for (int j = 0; j < 4; ++j) {
                    float v = acc[m][n][j] * g + bb;
                    if (RELU) v = fmaxf(v, 0.f);
                    if (BF16OUT)
                        ((uint16_t*)Cp)[(row + j) * (long long)Nstore + col] = f2bf(v);
                    else
                        ((float*)Cp)[(row + j) * (long long)Nstore + col] = v;
                }
            }
        }
    }
}

// ================= 128x128-tile GEMM with swizzle (layer 4) =================
template<bool RELU, bool BF16OUT>
__global__ __launch_bounds__(256) void gemm_bt(
    const uint16_t* __restrict__ A, const uint16_t* __restrict__ Bt,
    const float* __restrict__ bias, const float* __restrict__ gammas, int gi,
    void* __restrict__ Cp, int K, int Nstore, int Nvalid)
{
    constexpr int BK = 64;
    __shared__ char Atile[128 * 128];
    __shared__ char Btile[128 * 128];

    const int tid  = threadIdx.x;
    const int lane = tid & 63;
    const int wv   = tid >> 6;
    const int wr   = wv >> 1, wc = wv & 1;
    const long long tileM = (long long)blockIdx.y * 128;
    const long long tileN = (long long)blockIdx.x * 128;

    const float g = gammas[gi];

    f32x4 acc[4][4];
#pragma unroll
    for (int m = 0; m < 4; ++m)
#pragma unroll
        for (int n = 0; n < 4; ++n)
            acc[m][n] = (f32x4){0.f, 0.f, 0.f, 0.f};

    const int sr = tid >> 3;
    const int sc = ((tid & 7) * 8) ^ (((tid >> 3) & 7) * 8);
    const uint16_t* Ag = A  + (tileM + sr) * K + sc;
    const uint16_t* Bg = Bt + (tileN + sr) * K + sc;
    char* Ad = Atile + tid * 16;
    char* Bd = Btile + tid * 16;

    const int lr = lane & 15;
    const int klane = (lane >> 4) * 16;
    const int swz = (lr & 7) << 4;

    const int kIters = K / BK;
    for (int kt = 0; kt < kIters; ++kt) {
        const long long k0 = (long long)kt * BK;
        __syncthreads();
#pragma unroll
        for (int i = 0; i < 4; ++i) {
            load_lds16(Ag + (long long)(i * 32) * K + k0, Ad + i * 4096);
            load_lds16(Bg + (long long)(i * 32) * K + k0, Bd + i * 4096);
        }
        __syncthreads();
#pragma unroll
        for (int kk2 = 0; kk2 < 2; ++kk2) {
            const int cb = (kk2 * 64 + klane) ^ swz;
            bf16x8 a[4], b[4];
#pragma unroll
            for (int m = 0; m < 4; ++m)
                a[m] = *(const bf16x8*)(Atile + (wr * 64 + m * 16 + lr) * 128 + cb);
#pragma unroll
            for (int n = 0; n < 4; ++n)
                b[n] = *(const bf16x8*)(Btile + (wc * 64 + n * 16 + lr) * 128 + cb);
#pragma unroll
            for (int m = 0; m < 4; ++m)
#pragma unroll
                for (int n = 0; n < 4; ++n)
                    acc[m][n] = __builtin_amdgcn_mfma_f32_16x16x32_bf16(
                        a[m], b[n], acc[m][n], 0, 0, 0);
        }
    }

    const int cr = (lane >> 4) * 4;
    const int cc = lane & 15;
#pragma unroll
    for (int m = 0; m < 4; ++m) {
        const long long row = tileM + wr * 64 + m * 16 + cr;
#pragma unroll
        for (int n = 0; n < 4; ++n) {
            const int col = (int)tileN + wc * 64 + n * 16 + cc;
            if (col < Nvalid) {
                const float bb = bias[col];
#pragma unroll
                for (int j = 0; j < 4; ++j) {
                    float v = acc[m][n][j] * g + bb;
                    if (RELU) v = fmaxf(v, 0.f);
                    if (BF16OUT)
                        ((uint16_t*)Cp)[(row + j) * (long long)Nstore + col] = f2bf(v);
                    else
                        ((float*)Cp)[(row + j) * (long long)Nstore + col] = v;
                }
            }
        }
    }
}

extern "C" void kernel_launch(void* const* d_in, const int* in_sizes, int n_in,
                              void* d_out, int out_size, void* d_ws, size_t ws_size,
                              hipStream_t stream) {
    const float* x  = (const float*)d_in[0];
    const float* W1 = (const float*)d_in[1];
    const float* b1 = (const float*)d_in[2];
    const float* W2 = (const float*)d_in[3];
    const float* b2 = (const float*)d_in[4];
    const float* W3 = (const float*)d_in[5];
    const float* b3 = (const float*)d_in[6];
    const float* W4 = (const float*)d_in[7];
    const float* b4 = (const float*)d_in[8];
    float* out = (float*)d_out;

    const long long B = 8192, D = 4096, H = 4096, C = 1000, CPAD = 1024;

    char* ws = (char*)d_ws;
    float*  gammas  = (float*)ws;
    double* partial = (double*)(ws + 256);
    uint16_t* Q  = (uint16_t*)(ws + 32768);
    uint16_t* HA = Q  + (size_t)(H * H);
    uint16_t* HB = HA + (size_t)(B * H);

    const long long nW  = H * D;
    const long long nW4 = C * D;

    absmean_stage1<<<512, 256, 0, stream>>>(W1, nW,  partial + 0 * 512);
    absmean_stage1<<<512, 256, 0, stream>>>(W2, nW,  partial + 1 * 512);
    absmean_stage1<<<512, 256, 0, stream>>>(W3, nW,  partial + 2 * 512);
    absmean_stage1<<<512, 256, 0, stream>>>(W4, nW4, partial + 3 * 512);
    absmean_stage2<<<4, 256, 0, stream>>>(partial, gammas);

    cvt_bf16<<<2048, 256, 0, stream>>>(x, HA, B * D);

    const int gridN = (int)(H / 256);           // 16
    const int nwg   = gridN * (int)(B / 256);   // 512

    quantize_w<<<2048, 256, 0, stream>>>(W1, Q, nW, nW, gammas, 0);
    gemm256<true, true><<<dim3(nwg), dim3(512), 0, stream>>>(
        HA, Q, b1, gammas, 0, HB, (int)D, (int)H, (int)H, gridN);
    quantize_w<<<2048, 256, 0, stream>>>(W2, Q, nW, nW, gammas, 1);
    gemm256<true, true><<<dim3(nwg), dim3(512), 0, stream>>>(
        HB, Q, b2, gammas, 1, HA, (int)H, (int)H, (int)H, gridN);
    quantize_w<<<2048, 256, 0, stream>>>(W3, Q, nW, nW, gammas, 2);
    gemm256<true, true><<<dim3(nwg), dim3(512), 0, stream>>>(
        HA, Q, b3, gammas, 2, HB, (int)H, (int)H, (int)H, gridN);
    quantize_w<<<2048, 256, 0, stream>>>(W4, Q, nW4, CPAD * D, gammas, 3);
    gemm_bt<false, false><<<dim3((unsigned)(CPAD / 128), (unsigned)(B / 128)),
                            dim3(256), 0, stream>>>(
        HB, Q, b4, gammas, 3, out, (int)H, (int)C, (int)C);
}

// Round 6
// 884.345 us; speedup vs baseline: 2.4917x; 2.4917x over previous
//
#include <hip/hip_runtime.h>
#include <stdint.h>

// TernaryMLP: relu-chain of h @ (gamma*T).T + b, T ternary (exact in bf16).
// gamma via deterministic fp64 2-stage reduction; bf16 MFMA GEMMs.
// Layers 1-3: 256^2-tile 8-phase pipelined GEMM (R2-verified schedule:
//   same-phase read->barrier->lgkm0->MFMA, counted vmcnt(6), XOR swizzle,
//   XCD swizzle, setprio) + m201's lgkmcnt(8) hint in the 12-read phase.
// Layer 4 (N=1024): 128^2 2-phase GEMM with XOR swizzle.

#define EPSQ 1e-5f

typedef __attribute__((ext_vector_type(8))) short bf16x8;   // 8 bf16 = 4 VGPR
typedef __attribute__((ext_vector_type(4))) float f32x4;    // MFMA accum

__device__ __forceinline__ uint16_t f2bf(float f) {
    uint32_t u = __float_as_uint(f);
    return (uint16_t)((u + 0x7FFFu + ((u >> 16) & 1u)) >> 16);
}

__device__ __forceinline__ void load_lds16(const uint16_t* g, char* l) {
    __builtin_amdgcn_global_load_lds((const __attribute__((address_space(1))) void*)g,
                                     (__attribute__((address_space(3))) void*)l,
                                     16, 0, 0);
}

// ---------------- gamma = mean(|W|), deterministic fp64 2-stage ----------------
// One launch for all four matrices: blockIdx.y selects the matrix.
__global__ void absmean4(const float* __restrict__ w0, const float* __restrict__ w1,
                         const float* __restrict__ w2, const float* __restrict__ w3,
                         double* __restrict__ partial) {
    const int mi = blockIdx.y;
    const float* w = (mi == 0) ? w0 : (mi == 1) ? w1 : (mi == 2) ? w2 : w3;
    const long long n = (mi == 3) ? 4096000LL : 16777216LL;
    double acc = 0.0;
    const long long tid = (long long)blockIdx.x * blockDim.x + threadIdx.x;
    const long long stride = (long long)gridDim.x * blockDim.x;
    const float4* w4 = (const float4*)w;
    const long long n4 = n >> 2;
    for (long long i = tid; i < n4; i += stride) {
        float4 v = w4[i];
        acc += (double)fabsf(v.x) + (double)fabsf(v.y) +
               (double)fabsf(v.z) + (double)fabsf(v.w);
    }
    __shared__ double sm[256];
    sm[threadIdx.x] = acc;
    __syncthreads();
    for (int s = 128; s > 0; s >>= 1) {
        if ((int)threadIdx.x < s) sm[threadIdx.x] += sm[threadIdx.x + s];
        __syncthreads();
    }
    if (threadIdx.x == 0) partial[mi * 512 + blockIdx.x] = sm[0];
}

__global__ void absmean_stage2(const double* __restrict__ partial,
                               float* __restrict__ gammas) {
    const int m = blockIdx.x;
    __shared__ double sm[256];
    double acc = partial[m * 512 + threadIdx.x] + partial[m * 512 + 256 + threadIdx.x];
    sm[threadIdx.x] = acc;
    __syncthreads();
    for (int s = 128; s > 0; s >>= 1) {
        if ((int)threadIdx.x < s) sm[threadIdx.x] += sm[threadIdx.x + s];
        __syncthreads();
    }
    if (threadIdx.x == 0) {
        const double n = (m == 3) ? 1000.0 * 4096.0 : 4096.0 * 4096.0;
        gammas[m] = (float)(sm[0] / n);
    }
}

// ---------------- quantize W -> ternary bf16 (+ zero padding rows) ----------------
__global__ void quantize_w(const float* __restrict__ w, uint16_t* __restrict__ q,
                           long long n_valid, long long n_total,
                           const float* __restrict__ gammas, int gi) {
    const float d = gammas[gi] + EPSQ;
    const long long stride = (long long)gridDim.x * blockDim.x * 4;
    for (long long i = ((long long)blockIdx.x * blockDim.x + threadIdx.x) * 4;
         i < n_total; i += stride) {
        float4 v = make_float4(0.f, 0.f, 0.f, 0.f);
        if (i < n_valid) v = *(const float4*)(w + i);
        ushort4 o;
        o.x = f2bf(fminf(1.f, fmaxf(-1.f, rintf(v.x / d))));
        o.y = f2bf(fminf(1.f, fmaxf(-1.f, rintf(v.y / d))));
        o.z = f2bf(fminf(1.f, fmaxf(-1.f, rintf(v.z / d))));
        o.w = f2bf(fminf(1.f, fmaxf(-1.f, rintf(v.w / d))));
        *(ushort4*)(q + i) = o;
    }
}

// ---------------- x (fp32) -> bf16 ----------------
__global__ void cvt_bf16(const float* __restrict__ x, uint16_t* __restrict__ y,
                         long long n) {
    const long long stride = (long long)gridDim.x * blockDim.x * 4;
    for (long long i = ((long long)blockIdx.x * blockDim.x + threadIdx.x) * 4;
         i < n; i += stride) {
        float4 v = *(const float4*)(x + i);
        ushort4 o;
        o.x = f2bf(v.x); o.y = f2bf(v.y); o.z = f2bf(v.z); o.w = f2bf(v.w);
        *(ushort4*)(y + i) = o;
    }
}

// ================= 256x256-tile 8-phase GEMM (layers 1-3) =================
// C[m][n] = epi(gamma * sum_k A[m][k]*Bt[n][k] + bias[n])
// A:[M][K] bf16, Bt:[N][K] bf16. 512 thr = 8 waves (2M x 4N), per-wave 128x64.
// LDS 128KB: buf[2] x {A0,A1,B0,B1} halves of 128x64 bf16 (16KB each).
// Read swizzle: colbyte ^= (row&7)<<4; staged via inverse-swizzled global src.
template<bool RELU, bool BF16OUT>
__global__ __launch_bounds__(512, 2) void gemm256(
    const uint16_t* __restrict__ A, const uint16_t* __restrict__ Bt,
    const float* __restrict__ bias, const float* __restrict__ gammas, int gi,
    void* __restrict__ Cp, int K, int Nstore, int Nvalid, int gridN)
{
    __shared__ char lds[131072];

    const int tid  = threadIdx.x;
    const int lane = tid & 63;
    const int wid  = tid >> 6;
    const int wr   = wid >> 2;     // 0..1  -> A-half, C row block
    const int wc   = wid & 3;      // 0..3  -> C col block

    // T1: bijective XCD swizzle (gridDim.x % 8 == 0 for all our grids)
    const int nwg = gridDim.x;
    const int logical = ((int)blockIdx.x & 7) * (nwg >> 3) + ((int)blockIdx.x >> 3);
    const long long tileM = (long long)(logical / gridN) * 256;
    const long long tileN = (long long)(logical % gridN) * 256;

    // ---- staging addresses (inverse-swizzled global source, linear LDS dest) ----
    const int srow = tid >> 3;                                   // 0..63
    const int scol = (((tid & 7) ^ ((tid >> 3) & 7)) << 3);      // element offset
    const uint16_t* As = A  + (tileM + srow) * (long long)K + scol;
    const uint16_t* Bs = Bt + (tileN + srow) * (long long)K + scol;

    auto stageA = [&](int par, int h, int k0) {
        char* dst = lds + par * 65536 + h * 16384 + wid * 1024;
        const uint16_t* s = As + (long long)(h * 128) * K + k0;
        load_lds16(s, dst);
        load_lds16(s + (long long)64 * K, dst + 8192);
    };
    auto stageB = [&](int par, int h, int k0) {
        char* dst = lds + par * 65536 + 32768 + h * 16384 + wid * 1024;
        const uint16_t* s = Bs + (long long)(h * 128) * K + k0;
        load_lds16(s, dst);
        load_lds16(s + (long long)64 * K, dst + 8192);
    };

    // ---- fragment read addressing (swizzled) ----
    const int lr   = lane & 15;
    const int cb0  = (lane >> 4) << 4;        // 0,16,32,48 (k-quarter byte)
    const int swz  = (lane & 7) << 4;
    const int colk0 = cb0 ^ swz;
    const int colk1 = (cb0 | 64) ^ swz;
    const int Aoff = wr * 16384 + lr * 128;
    const int Boff = 32768 + (wc >> 1) * 16384 + ((wc & 1) * 64 + lr) * 128;

    f32x4 acc[8][4];
#pragma unroll
    for (int m = 0; m < 8; ++m)
#pragma unroll
        for (int n = 0; n < 4; ++n)
            acc[m][n] = (f32x4){0.f, 0.f, 0.f, 0.f};

    const int NT = K >> 6;   // 64 K-tiles

    // ---- prologue: tile0 all 4 halves + t1.{B0,B1,A0}; 3 half-tiles in flight ----
    stageA(0, 0, 0); stageA(0, 1, 0);
    stageB(0, 0, 0); stageB(0, 1, 0);
    stageB(1, 0, 64); stageB(1, 1, 64);
    stageA(1, 0, 64);
    asm volatile("s_waitcnt vmcnt(6)" ::: "memory");
    __builtin_amdgcn_s_barrier();

    auto do_tile = [&](int t, int par) {
        const char* Ab = lds + par * 65536 + Aoff;
        const char* Bb = lds + par * 65536 + Boff;
        const int k1 = (t + 1) * 64;
        const int k2 = (t + 2) * 64;
        bf16x8 bfr[2][4];
        bf16x8 afr[2][2];

        // ---- phase 0: all b-frags + a-frags m0,m1; stage (t+1).A1 ----
#pragma unroll
        for (int kk = 0; kk < 2; ++kk) {
            const int ck = kk ? colk1 : colk0;
#pragma unroll
            for (int n = 0; n < 4; ++n)
                bfr[kk][n] = *(const bf16x8*)(Bb + n * 2048 + ck);
#pragma unroll
            for (int mm = 0; mm < 2; ++mm)
                afr[kk][mm] = *(const bf16x8*)(Ab + mm * 2048 + ck);
        }
        if (t + 1 < NT) stageA(1 - par, 1, k1);
        asm volatile("s_waitcnt lgkmcnt(8)" ::: "memory");   // m201 hint: 12-read phase
        __builtin_amdgcn_s_barrier();
        asm volatile("s_waitcnt lgkmcnt(0)" ::: "memory");
        __builtin_amdgcn_sched_barrier(0);
        __builtin_amdgcn_s_setprio(1);
#pragma unroll
        for (int kk = 0; kk < 2; ++kk)
#pragma unroll
            for (int mm = 0; mm < 2; ++mm)
#pragma unroll
                for (int n = 0; n < 4; ++n)
                    acc[mm][n] = __builtin_amdgcn_mfma_f32_16x16x32_bf16(
                        afr[kk][mm], bfr[kk][n], acc[mm][n], 0, 0, 0);
        __builtin_amdgcn_s_setprio(0);
        __builtin_amdgcn_s_barrier();

        // ---- phases 1..3 ----
#pragma unroll
        for (int p = 1; p < 4; ++p) {
#pragma unroll
            for (int kk = 0; kk < 2; ++kk) {
                const int ck = kk ? colk1 : colk0;
#pragma unroll
                for (int mm = 0; mm < 2; ++mm)
                    afr[kk][mm] = *(const bf16x8*)(Ab + (2 * p + mm) * 2048 + ck);
            }
            if (p == 1 && t + 2 < NT) stageB(par, 0, k2);   // B0 dead after phase 0
            if (p == 2 && t + 2 < NT) stageB(par, 1, k2);
            __builtin_amdgcn_s_barrier();
            asm volatile("s_waitcnt lgkmcnt(0)" ::: "memory");
            __builtin_amdgcn_sched_barrier(0);
            if (p == 3 && t + 2 < NT) stageA(par, 0, k2);   // this tile's A-reads done
            __builtin_amdgcn_s_setprio(1);
#pragma unroll
            for (int kk = 0; kk < 2; ++kk)
#pragma unroll
                for (int mm = 0; mm < 2; ++mm)
#pragma unroll
                    for (int n = 0; n < 4; ++n)
                        acc[2 * p + mm][n] = __builtin_amdgcn_mfma_f32_16x16x32_bf16(
                            afr[kk][mm], bfr[kk][n], acc[2 * p + mm][n], 0, 0, 0);
            __builtin_amdgcn_s_setprio(0);
            if (p == 3) {
                if (t < NT - 2)
                    asm volatile("s_waitcnt vmcnt(6)" ::: "memory");
                else if (t == NT - 2)
                    asm volatile("s_waitcnt vmcnt(0)" ::: "memory");
            }
            __builtin_amdgcn_s_barrier();
        }
    };

    for (int t = 0; t < NT; t += 2) {
        do_tile(t, 0);
        do_tile(t + 1, 1);
    }

    // ---- epilogue ----
    const float g = gammas[gi];
    const int cr = (lane >> 4) << 2;
    const int cc = lane & 15;
#pragma unroll
    for (int m = 0; m < 8; ++m) {
        const long long row = tileM + wr * 128 + m * 16 + cr;
#pragma unroll
        for (int n = 0; n < 4; ++n) {
            const int col = (int)tileN + wc * 64 + n * 16 + cc;
            if (col < Nvalid) {
                const float bb = bias[col];
#pragma unroll
                for (int j = 0; j < 4; ++j) {
                    float v = acc[m][n][j] * g + bb;
                    if (RELU) v = fmaxf(v, 0.f);
                    if (BF16OUT)
                        ((uint16_t*)Cp)[(row + j) * (long long)Nstore + col] = f2bf(v);
                    else
                        ((float*)Cp)[(row + j) * (long long)Nstore + col] = v;
                }
            }
        }
    }
}

// ================= 128x128-tile GEMM with swizzle (layer 4) =================
template<bool RELU, bool BF16OUT>
__global__ __launch_bounds__(256) void gemm_bt(
    const uint16_t* __restrict__ A, const uint16_t* __restrict__ Bt,
    const float* __restrict__ bias, const float* __restrict__ gammas, int gi,
    void* __restrict__ Cp, int K, int Nstore, int Nvalid)
{
    constexpr int BK = 64;
    __shared__ char Atile[128 * 128];
    __shared__ char Btile[128 * 128];

    const int tid  = threadIdx.x;
    const int lane = tid & 63;
    const int wv   = tid >> 6;
    const int wr   = wv >> 1, wc = wv & 1;
    const long long tileM = (long long)blockIdx.y * 128;
    const long long tileN = (long long)blockIdx.x * 128;

    const float g = gammas[gi];

    f32x4 acc[4][4];
#pragma unroll
    for (int m = 0; m < 4; ++m)
#pragma unroll
        for (int n = 0; n < 4; ++n)
            acc[m][n] = (f32x4){0.f, 0.f, 0.f, 0.f};

    const int sr = tid >> 3;
    const int sc = ((tid & 7) * 8) ^ (((tid >> 3) & 7) * 8);
    const uint16_t* Ag = A  + (tileM + sr) * K + sc;
    const uint16_t* Bg = Bt + (tileN + sr) * K + sc;
    char* Ad = Atile + tid * 16;
    char* Bd = Btile + tid * 16;

    const int lr = lane & 15;
    const int klane = (lane >> 4) * 16;
    const int swz = (lr & 7) << 4;

    const int kIters = K / BK;
    for (int kt = 0; kt < kIters; ++kt) {
        const long long k0 = (long long)kt * BK;
        __syncthreads();
#pragma unroll
        for (int i = 0; i < 4; ++i) {
            load_lds16(Ag + (long long)(i * 32) * K + k0, Ad + i * 4096);
            load_lds16(Bg + (long long)(i * 32) * K + k0, Bd + i * 4096);
        }
        __syncthreads();
#pragma unroll
        for (int kk2 = 0; kk2 < 2; ++kk2) {
            const int cb = (kk2 * 64 + klane) ^ swz;
            bf16x8 a[4], b[4];
#pragma unroll
            for (int m = 0; m < 4; ++m)
                a[m] = *(const bf16x8*)(Atile + (wr * 64 + m * 16 + lr) * 128 + cb);
#pragma unroll
            for (int n = 0; n < 4; ++n)
                b[n] = *(const bf16x8*)(Btile + (wc * 64 + n * 16 + lr) * 128 + cb);
#pragma unroll
            for (int m = 0; m < 4; ++m)
#pragma unroll
                for (int n = 0; n < 4; ++n)
                    acc[m][n] = __builtin_amdgcn_mfma_f32_16x16x32_bf16(
                        a[m], b[n], acc[m][n], 0, 0, 0);
        }
    }

    const int cr = (lane >> 4) * 4;
    const int cc = lane & 15;
#pragma unroll
    for (int m = 0; m < 4; ++m) {
        const long long row = tileM + wr * 64 + m * 16 + cr;
#pragma unroll
        for (int n = 0; n < 4; ++n) {
            const int col = (int)tileN + wc * 64 + n * 16 + cc;
            if (col < Nvalid) {
                const float bb = bias[col];
#pragma unroll
                for (int j = 0; j < 4; ++j) {
                    float v = acc[m][n][j] * g + bb;
                    if (RELU) v = fmaxf(v, 0.f);
                    if (BF16OUT)
                        ((uint16_t*)Cp)[(row + j) * (long long)Nstore + col] = f2bf(v);
                    else
                        ((float*)Cp)[(row + j) * (long long)Nstore + col] = v;
                }
            }
        }
    }
}

extern "C" void kernel_launch(void* const* d_in, const int* in_sizes, int n_in,
                              void* d_out, int out_size, void* d_ws, size_t ws_size,
                              hipStream_t stream) {
    const float* x  = (const float*)d_in[0];
    const float* W1 = (const float*)d_in[1];
    const float* b1 = (const float*)d_in[2];
    const float* W2 = (const float*)d_in[3];
    const float* b2 = (const float*)d_in[4];
    const float* W3 = (const float*)d_in[5];
    const float* b3 = (const float*)d_in[6];
    const float* W4 = (const float*)d_in[7];
    const float* b4 = (const float*)d_in[8];
    float* out = (float*)d_out;

    const long long B = 8192, D = 4096, H = 4096, C = 1000, CPAD = 1024;

    char* ws = (char*)d_ws;
    float*  gammas  = (float*)ws;
    double* partial = (double*)(ws + 256);
    uint16_t* Q  = (uint16_t*)(ws + 32768);
    uint16_t* HA = Q  + (size_t)(H * H);
    uint16_t* HB = HA + (size_t)(B * H);

    const long long nW  = H * D;
    const long long nW4 = C * D;

    absmean4<<<dim3(512, 4), 256, 0, stream>>>(W1, W2, W3, W4, partial);
    absmean_stage2<<<4, 256, 0, stream>>>(partial, gammas);

    cvt_bf16<<<2048, 256, 0, stream>>>(x, HA, B * D);

    const int gridN = (int)(H / 256);           // 16
    const int nwg   = gridN * (int)(B / 256);   // 512

    quantize_w<<<2048, 256, 0, stream>>>(W1, Q, nW, nW, gammas, 0);
    gemm256<true, true><<<dim3(nwg), dim3(512), 0, stream>>>(
        HA, Q, b1, gammas, 0, HB, (int)D, (int)H, (int)H, gridN);
    quantize_w<<<2048, 256, 0, stream>>>(W2, Q, nW, nW, gammas, 1);
    gemm256<true, true><<<dim3(nwg), dim3(512), 0, stream>>>(
        HB, Q, b2, gammas, 1, HA, (int)H, (int)H, (int)H, gridN);
    quantize_w<<<2048, 256, 0, stream>>>(W3, Q, nW, nW, gammas, 2);
    gemm256<true, true><<<dim3(nwg), dim3(512), 0, stream>>>(
        HA, Q, b3, gammas, 2, HB, (int)H, (int)H, (int)H, gridN);
    quantize_w<<<2048, 256, 0, stream>>>(W4, Q, nW4, CPAD * D, gammas, 3);
    gemm_bt<false, false><<<dim3((unsigned)(CPAD / 128), (unsigned)(B / 128)),
                            dim3(256), 0, stream>>>(
        HB, Q, b4, gammas, 3, out, (int)H, (int)C, (int)C);
}